// Round 7
// baseline (3599.712 us; speedup 1.0000x reference)
//
#include <hip/hip_runtime.h>

#define BATCH   512
#define TSTEPS  50
#define NIN     784
#define NHID    800
#define NOUT    10
#define KC      384   // OpenBLAS SGEMM_DEFAULT_Q — panel folds at k=384, 768
#define GRP     8     // rows per spmm block

// ---------------------------------------------------------------------------
// Dense f32 GEMM (NT), OpenBLAS-rounding-exact (layer 1).
// 128x128 tile, 8x8 micro, BK=8, k-major LDS (swizzled B), panel-spill to C.
// Per element: ascending-k FMA chain per KC-panel; C = ((P1+P2)+P3).
// Requires M%128==0, K%8==0, K<=1152, N%4==0.
// ---------------------------------------------------------------------------
__global__ __launch_bounds__(256, 4)
void gemm_nt_f32(const float* __restrict__ A, const float* __restrict__ B,
                 float* __restrict__ C, int M, int N, int K)
{
    __shared__ float As[8][132];   // [k][m], stride 528B (16B-aligned)
    __shared__ float Bs[8][188];   // [k][phys(n)], phys=12*(n>>3)+(n&7)

    const int tid = threadIdx.x;
    const int tx = tid & 15;        // n micro: 8 cols at 8*tx
    const int ty = tid >> 4;        // m micro: 8 rows at 8*ty
    const int m0 = blockIdx.x * 128;
    const int n0 = blockIdx.y * 128;

    // staging: thread loads one float4 of A and one of B per 8-k chunk
    const int srow = tid >> 1;          // 0..127
    const int skq  = (tid & 1) * 4;     // 0 or 4
    const int bphys = 12 * (srow >> 3) + (srow & 7);

    const float* Aptr = A + (size_t)(m0 + srow) * K + skq;
    const float* Bptr = B + (size_t)(n0 + srow) * K + skq;
    const bool bval = (n0 + srow) < N;

    const int cb = n0 + 8 * tx;
    const bool q0v = (cb + 4 <= N);
    const bool q1v = (cb + 8 <= N);

    float part[8][8];
    #pragma unroll
    for (int i = 0; i < 8; ++i)
        #pragma unroll
        for (int j = 0; j < 8; ++j) part[i][j] = 0.0f;

    float4 av = *(const float4*)(Aptr);
    float4 bv = bval ? *(const float4*)(Bptr) : make_float4(0.f,0.f,0.f,0.f);

    for (int k0 = 0; k0 < K; k0 += 8) {
        __syncthreads();
        As[skq+0][srow] = av.x; As[skq+1][srow] = av.y;
        As[skq+2][srow] = av.z; As[skq+3][srow] = av.w;
        Bs[skq+0][bphys] = bv.x; Bs[skq+1][bphys] = bv.y;
        Bs[skq+2][bphys] = bv.z; Bs[skq+3][bphys] = bv.w;
        __syncthreads();

        if (k0 + 8 < K) {
            av = *(const float4*)(Aptr + k0 + 8);
            bv = bval ? *(const float4*)(Bptr + k0 + 8) : make_float4(0.f,0.f,0.f,0.f);
        }

        // KC-panel fold: spill partial sums into C (P1, then P1+P2)
        if (k0 == 384 || k0 == 768) {
            const bool first = (k0 == 384);
            #pragma unroll
            for (int i = 0; i < 8; ++i) {
                float* crow = C + (size_t)(m0 + 8*ty + i) * N + cb;
                if (q0v) {
                    if (first) {
                        *(float4*)crow = make_float4(part[i][0], part[i][1],
                                                     part[i][2], part[i][3]);
                    } else {
                        float4 o = *(const float4*)crow;
                        o.x = __fadd_rn(o.x, part[i][0]);
                        o.y = __fadd_rn(o.y, part[i][1]);
                        o.z = __fadd_rn(o.z, part[i][2]);
                        o.w = __fadd_rn(o.w, part[i][3]);
                        *(float4*)crow = o;
                    }
                }
                if (q1v) {
                    if (first) {
                        *(float4*)(crow + 4) = make_float4(part[i][4], part[i][5],
                                                           part[i][6], part[i][7]);
                    } else {
                        float4 o = *(const float4*)(crow + 4);
                        o.x = __fadd_rn(o.x, part[i][4]);
                        o.y = __fadd_rn(o.y, part[i][5]);
                        o.z = __fadd_rn(o.z, part[i][6]);
                        o.w = __fadd_rn(o.w, part[i][7]);
                        *(float4*)(crow + 4) = o;
                    }
                }
                #pragma unroll
                for (int j = 0; j < 8; ++j) part[i][j] = 0.0f;
            }
        }

        #pragma unroll
        for (int kk = 0; kk < 8; ++kk) {
            float a[8], b[8];
            *(float4*)&a[0] = *(const float4*)&As[kk][8*ty];
            *(float4*)&a[4] = *(const float4*)&As[kk][8*ty + 4];
            *(float4*)&b[0] = *(const float4*)&Bs[kk][12*tx];
            *(float4*)&b[4] = *(const float4*)&Bs[kk][12*tx + 4];
            #pragma unroll
            for (int i = 0; i < 8; ++i)
                #pragma unroll
                for (int j = 0; j < 8; ++j)
                    part[i][j] = __fmaf_rn(a[i], b[j], part[i][j]);
        }
    }

    // epilogue: C = spilled(P1+P2) + P3   (or = part if K <= KC)
    const bool folded = (K > KC);
    #pragma unroll
    for (int i = 0; i < 8; ++i) {
        float* crow = C + (size_t)(m0 + 8*ty + i) * N + cb;
        if (q0v) {
            float4 o;
            if (folded) {
                o = *(const float4*)crow;
                o.x = __fadd_rn(o.x, part[i][0]); o.y = __fadd_rn(o.y, part[i][1]);
                o.z = __fadd_rn(o.z, part[i][2]); o.w = __fadd_rn(o.w, part[i][3]);
            } else {
                o = make_float4(part[i][0], part[i][1], part[i][2], part[i][3]);
            }
            *(float4*)crow = o;
        }
        if (q1v) {
            float4 o;
            if (folded) {
                o = *(const float4*)(crow + 4);
                o.x = __fadd_rn(o.x, part[i][4]); o.y = __fadd_rn(o.y, part[i][5]);
                o.z = __fadd_rn(o.z, part[i][6]); o.w = __fadd_rn(o.w, part[i][7]);
            } else {
                o = make_float4(part[i][4], part[i][5], part[i][6], part[i][7]);
            }
            *(float4*)(crow + 4) = o;
        }
    }
}

// ---------------------------------------------------------------------------
// 800x800 transpose: W2T[k][n] = W2[n][k]
// ---------------------------------------------------------------------------
__global__ __launch_bounds__(256)
void transpose800(const float* __restrict__ W2, float* __restrict__ W2T)
{
    __shared__ float t[32][33];
    const int tx  = threadIdx.x & 31;
    const int ty8 = threadIdx.x >> 5;
    const int bx = blockIdx.x * 32, by = blockIdx.y * 32;

    #pragma unroll
    for (int r = 0; r < 4; ++r) {
        int a = ty8 + r * 8;
        t[a][tx] = W2[(size_t)(by + a) * 800 + bx + tx];
    }
    __syncthreads();
    #pragma unroll
    for (int r = 0; r < 4; ++r) {
        int a = ty8 + r * 8;
        W2T[(size_t)(bx + a) * 800 + by + tx] = t[tx][a];
    }
}

// ---------------------------------------------------------------------------
// LIF scan for hidden layers (Nn=800), block per batch row, emits bitmask.
// ---------------------------------------------------------------------------
__global__ __launch_bounds__(256)
void lif_scan_hid(const float* __restrict__ Z,
                  const float* __restrict__ bias,
                  const float* __restrict__ budget,
                  float* __restrict__ mcarry,
                  float* __restrict__ Sout,
                  unsigned long long* __restrict__ bm,
                  int CT, int t0)
{
    const int b = blockIdx.x;
    const int tid = threadIdx.x;
    const int lane = tid & 63;
    const int wave = tid >> 6;

    float m[4], thr[4], bj[4];
    bool val[4];
    #pragma unroll
    for (int c = 0; c < 4; ++c) {
        const int j = c * 256 + tid;
        val[c] = (j < NHID);
        const int jj = val[c] ? j : 0;
        float bu = budget[jj];
        bu = fminf(fmaxf(bu, 0.01f), 1.0f);
        thr[c] = __fdiv_rn(1.0f, bu);
        bj[c]  = bias[jj];
        m[c]   = mcarry[b * NHID + jj];
    }

    for (int ct = 0; ct < CT; ++ct) {
        const size_t zbase = (size_t)ct * (BATCH * NHID) + (size_t)b * NHID;
        const size_t sbase = (size_t)(t0 + ct) * (BATCH * NHID) + (size_t)b * NHID;
        #pragma unroll
        for (int c = 0; c < 4; ++c) {
            const int j = c * 256 + tid;
            bool sp = false;
            if (val[c]) {
                float z = Z[zbase + j];
                float mm = __fadd_rn(__fadd_rn(__fmul_rn(0.95f, m[c]), z), bj[c]);
                sp = (mm > thr[c]);
                m[c] = sp ? 0.0f : mm;
                Sout[sbase + j] = sp ? 1.0f : 0.0f;
            }
            unsigned long long bits = __ballot(sp);
            if (bm && lane == 0) {
                const int W = c * 4 + wave;
                if (W < 13)
                    bm[((size_t)ct * BATCH + b) * 13 + W] = bits;
            }
        }
    }
    #pragma unroll
    for (int c = 0; c < 4; ++c)
        if (val[c]) mcarry[b * NHID + c * 256 + tid] = m[c];
}

// ---------------------------------------------------------------------------
// Sparse spike GEMM, 8 rows per block sharing W2T reads.
// Union bitmask walk (ascending k, wave-uniform); per-row uniform branches.
// Bit-exact: skipped k leaves chain unchanged; active k is fadd(part, w).
// ---------------------------------------------------------------------------
__global__ __launch_bounds__(256, 4)
void spmm_spikes(const unsigned long long* __restrict__ bm, // [rows][13]
                 const float* __restrict__ W2T,             // [800][800]
                 float* __restrict__ Z,                     // [rows][800]
                 int rows)
{
    const int tid = threadIdx.x;
    const int row0 = blockIdx.x * GRP;
    const bool act = (tid < 200);
    const int n = 4 * (act ? tid : 0);

    float part[GRP][4], acc[GRP][4];
    #pragma unroll
    for (int r = 0; r < GRP; ++r)
        #pragma unroll
        for (int j = 0; j < 4; ++j) { part[r][j] = 0.0f; acc[r][j] = 0.0f; }

    int p = 0, nextb = KC;

    for (int w = 0; w < 13; ++w) {
        unsigned long long rm[GRP], u = 0ull;
        #pragma unroll
        for (int r = 0; r < GRP; ++r) {
            rm[r] = bm[(size_t)(row0 + r) * 13 + w];
            u |= rm[r];
        }
        while (u) {
            const int b = __ffsll((unsigned long long)u) - 1;
            u &= u - 1ull;
            const int k = w * 64 + b;
            while (k >= nextb) {          // close panel(s)
                #pragma unroll
                for (int r = 0; r < GRP; ++r)
                    #pragma unroll
                    for (int j = 0; j < 4; ++j) {
                        acc[r][j] = (p == 0) ? part[r][j]
                                             : __fadd_rn(acc[r][j], part[r][j]);
                        part[r][j] = 0.0f;
                    }
                ++p;
                nextb = (nextb == KC) ? 2 * KC : 0x7FFFFFFF;
            }
            const float4 wq = *(const float4*)(W2T + (size_t)k * NHID + n);
            #pragma unroll
            for (int r = 0; r < GRP; ++r) {
                if (__builtin_amdgcn_readfirstlane(
                        (unsigned)((rm[r] >> b) & 1ull))) {
                    part[r][0] = __fadd_rn(part[r][0], wq.x);
                    part[r][1] = __fadd_rn(part[r][1], wq.y);
                    part[r][2] = __fadd_rn(part[r][2], wq.z);
                    part[r][3] = __fadd_rn(part[r][3], wq.w);
                }
            }
        }
    }
    while (p < 3) {                       // close remaining panels (K=800 -> 3)
        #pragma unroll
        for (int r = 0; r < GRP; ++r)
            #pragma unroll
            for (int j = 0; j < 4; ++j) {
                acc[r][j] = (p == 0) ? part[r][j]
                                     : __fadd_rn(acc[r][j], part[r][j]);
                part[r][j] = 0.0f;
            }
        ++p;
    }
    if (act) {
        #pragma unroll
        for (int r = 0; r < GRP; ++r)
            *(float4*)(Z + (size_t)(row0 + r) * NHID + n) =
                make_float4(acc[r][0], acc[r][1], acc[r][2], acc[r][3]);
    }
}

// ---------------------------------------------------------------------------
__global__ __launch_bounds__(256)
void gemm3_f32(const float* __restrict__ S2, const float* __restrict__ W3,
               float* __restrict__ Z3, int rows)
{
    int gid = blockIdx.x * 256 + threadIdx.x;
    if (gid >= rows * NOUT) return;
    const int m = gid / NOUT;
    const int nn = gid % NOUT;
    const float* a = S2 + (size_t)m * NHID;
    const float* wr = W3 + (size_t)nn * NHID;

    float acc = 0.0f;
    for (int p0 = 0; p0 < NHID; p0 += KC) {
        const int pend = (p0 + KC < NHID) ? (p0 + KC) : NHID;
        float part = 0.0f;
        for (int k = p0; k < pend; ++k)
            part = __fmaf_rn(a[k], wr[k], part);
        acc = (p0 == 0) ? part : __fadd_rn(acc, part);
    }
    Z3[gid] = acc;
}

// ---------------------------------------------------------------------------
__global__ __launch_bounds__(256)
void lif_scan_small(const float* __restrict__ Z, const float* __restrict__ bias,
                    float* __restrict__ mcarry, float* __restrict__ Sout,
                    int CT, int t0)
{
    const int idx = blockIdx.x * blockDim.x + threadIdx.x;
    const int total = BATCH * NOUT;
    if (idx >= total) return;
    const int j = idx % NOUT;
    const float thr = 1.0f;
    const float bj = bias[j];

    float m = mcarry[idx];
    for (int ct = 0; ct < CT; ++ct) {
        float z = Z[(size_t)ct * total + idx];
        m = __fadd_rn(__fadd_rn(__fmul_rn(0.95f, m), z), bj);
        float s;
        if (m > thr) { s = 1.0f; m = 0.0f; }
        else         { s = 0.0f; }
        Sout[(size_t)(t0 + ct) * total + idx] = s;
    }
    mcarry[idx] = m;
}

// ---------------------------------------------------------------------------
__global__ __launch_bounds__(256)
void sum_t(const float* __restrict__ S3, float* __restrict__ out0)
{
    const int idx = blockIdx.x * blockDim.x + threadIdx.x;
    if (idx >= BATCH * NOUT) return;
    float s = 0.0f;
    for (int t = 0; t < TSTEPS; ++t)
        s += S3[(size_t)t * BATCH * NOUT + idx];
    out0[idx] = s;
}

// ---------------------------------------------------------------------------
extern "C" void kernel_launch(void* const* d_in, const int* in_sizes, int n_in,
                              void* d_out, int out_size, void* d_ws, size_t ws_size,
                              hipStream_t stream)
{
    const float* x       = (const float*)d_in[0];
    const float* W1      = (const float*)d_in[1];
    const float* b1      = (const float*)d_in[2];
    const float* W2      = (const float*)d_in[3];
    const float* b2      = (const float*)d_in[4];
    const float* W3      = (const float*)d_in[5];
    const float* b3      = (const float*)d_in[6];
    const float* budget1 = (const float*)d_in[7];
    const float* budget2 = (const float*)d_in[8];

    float* out  = (float*)d_out;
    float* out0 = out;
    float* out1 = out0 + BATCH * NOUT;
    float* out2 = out1 + (size_t)TSTEPS * BATCH * NHID;
    float* out3 = out2 + (size_t)TSTEPS * BATCH * NHID;

    const size_t nBH = (size_t)BATCH * NHID;
    const size_t nBO = (size_t)BATCH * NOUT;
    float* m1c = (float*)d_ws;
    float* m2c = m1c + nBH;
    float* m3c = m2c + nBH;
    float* w2t = m3c + nBO;
    unsigned long long* bmask = (unsigned long long*)(w2t + (size_t)NHID * NHID);
    float* Z = (float*)(bmask + (size_t)TSTEPS * BATCH * 13);

    const size_t fixedF = 2 * nBH + nBO + (size_t)NHID * NHID
                        + (size_t)TSTEPS * BATCH * 13 * 2;
    size_t availF = (ws_size / 4 > fixedF) ? (ws_size / 4 - fixedF) : 0;
    const size_t perT = (size_t)BATCH * (NHID + NOUT);
    int CT = (int)(availF / perT);
    if (CT > TSTEPS) CT = TSTEPS;
    if (CT < 1) CT = 1;

    hipMemsetAsync(d_ws, 0, (2 * nBH + nBO) * sizeof(float), stream);

    {
        dim3 tg(25, 25);
        transpose800<<<tg, 256, 0, stream>>>(W2, w2t);
    }

    for (int t0 = 0; t0 < TSTEPS; t0 += CT) {
        int ct = TSTEPS - t0 < CT ? TSTEPS - t0 : CT;
        int Mrows = ct * BATCH;
        float* Z3 = Z + (size_t)ct * BATCH * NHID;

        // layer 1: dense Z = x_chunk @ W1^T
        {
            dim3 grid(Mrows / 128, (NHID + 127) / 128);
            gemm_nt_f32<<<grid, 256, 0, stream>>>(
                x + (size_t)t0 * BATCH * NIN, W1, Z, Mrows, NHID, NIN);
        }
        lif_scan_hid<<<BATCH, 256, 0, stream>>>(
            Z, b1, budget1, m1c, out1, bmask, ct, t0);

        // layer 2: sparse Z = s1_chunk @ W2^T via bitmask (8 rows/block)
        spmm_spikes<<<Mrows / GRP, 256, 0, stream>>>(bmask, w2t, Z, Mrows);
        lif_scan_hid<<<BATCH, 256, 0, stream>>>(
            Z, b2, budget2, m2c, out2, nullptr, ct, t0);

        // layer 3
        gemm3_f32<<<(Mrows * NOUT + 255) / 256, 256, 0, stream>>>(
            out2 + (size_t)t0 * BATCH * NHID, W3, Z3, Mrows);
        lif_scan_small<<<(BATCH * NOUT + 255) / 256, 256, 0, stream>>>(
            Z3, b3, m3c, out3, ct, t0);
    }

    sum_t<<<(BATCH * NOUT + 255) / 256, 256, 0, stream>>>(out3, out0);
}

// Round 8
// 1542.789 us; speedup vs baseline: 2.3332x; 2.3332x over previous
//
#include <hip/hip_runtime.h>

#define BATCH   512
#define TSTEPS  50
#define NIN     784
#define NHID    800
#define NOUT    10
#define KC      384   // OpenBLAS SGEMM_DEFAULT_Q — panel folds at k=384, 768
#define GRP     8     // rows per spmm block

// ---------------------------------------------------------------------------
// Dense f32 GEMM (NT), OpenBLAS-rounding-exact (layer 1).
// 128x64 tile, 8x4 micro, BK=16 (half the barriers of BK=8), k-major LDS,
// register prefetch. Plain launch_bounds: (256,4) empirically caps VGPR at 64
// on hipcc and forces scratch spill (round-7 catastrophe).
// Per element: ascending-k FMA chain per KC-panel; C = ((P1+P2)+P3).
// Requires M%128==0, K%16==0, K<=1152.
// ---------------------------------------------------------------------------
__global__ __launch_bounds__(256)
void gemm_nt_f32(const float* __restrict__ A, const float* __restrict__ B,
                 float* __restrict__ C, int M, int N, int K)
{
    __shared__ float As[16][132];   // [k][m]
    __shared__ float Bs[16][68];    // [k][n]

    const int tid = threadIdx.x;
    const int tx = tid & 15;        // n micro: cols 4*tx
    const int ty = tid >> 4;        // m micro: rows 8*ty
    const int m0 = blockIdx.x * 128;
    const int n0 = blockIdx.y * 64;

    // A staging: row m0+(tid>>1), k-8-group (tid&1)*8  (two float4)
    const int arow = tid >> 1;          // 0..127
    const int akq  = (tid & 1) * 8;     // 0 or 8
    // B staging: row n0+(tid>>2), k-quad (tid&3)*4     (one float4)
    const int brow = tid >> 2;          // 0..63
    const int bkq  = (tid & 3) * 4;     // 0,4,8,12

    const float* Aptr = A + (size_t)(m0 + arow) * K + akq;
    const float* Bptr = B + (size_t)(n0 + brow) * K + bkq;
    const bool bval = (n0 + brow) < N;

    float part[8][4];   // current KC-panel chain
    float acc[8][4];    // folded closed panels
    #pragma unroll
    for (int i = 0; i < 8; ++i)
        #pragma unroll
        for (int j = 0; j < 4; ++j) part[i][j] = 0.0f;

    float4 av0 = *(const float4*)(Aptr);
    float4 av1 = *(const float4*)(Aptr + 4);
    float4 bv  = bval ? *(const float4*)(Bptr) : make_float4(0.f,0.f,0.f,0.f);

    for (int k0 = 0; k0 < K; k0 += 16) {
        __syncthreads();
        As[akq+0][arow] = av0.x; As[akq+1][arow] = av0.y;
        As[akq+2][arow] = av0.z; As[akq+3][arow] = av0.w;
        As[akq+4][arow] = av1.x; As[akq+5][arow] = av1.y;
        As[akq+6][arow] = av1.z; As[akq+7][arow] = av1.w;
        Bs[bkq+0][brow] = bv.x;  Bs[bkq+1][brow] = bv.y;
        Bs[bkq+2][brow] = bv.z;  Bs[bkq+3][brow] = bv.w;
        __syncthreads();

        // prefetch next chunk (hides under 64x16 FMA block)
        if (k0 + 16 < K) {
            av0 = *(const float4*)(Aptr + k0 + 16);
            av1 = *(const float4*)(Aptr + k0 + 20);
            bv  = bval ? *(const float4*)(Bptr + k0 + 16)
                       : make_float4(0.f,0.f,0.f,0.f);
        }

        // KC-panel fold (uniform branch; k0 in {384, 768}, both %16==0)
        if (k0 == 384 || k0 == 768) {
            #pragma unroll
            for (int i = 0; i < 8; ++i)
                #pragma unroll
                for (int j = 0; j < 4; ++j) {
                    acc[i][j] = (k0 == 384) ? part[i][j]
                                            : __fadd_rn(acc[i][j], part[i][j]);
                    part[i][j] = 0.0f;
                }
        }

        #pragma unroll
        for (int kk = 0; kk < 16; ++kk) {
            float a[8], b[4];
            *(float4*)&a[0] = *(const float4*)&As[kk][8*ty];
            *(float4*)&a[4] = *(const float4*)&As[kk][8*ty + 4];
            *(float4*)&b[0] = *(const float4*)&Bs[kk][4*tx];
            #pragma unroll
            for (int i = 0; i < 8; ++i)
                #pragma unroll
                for (int j = 0; j < 4; ++j)
                    part[i][j] = __fmaf_rn(a[i], b[j], part[i][j]);
        }
    }

    #pragma unroll
    for (int i = 0; i < 8; ++i)
        #pragma unroll
        for (int j = 0; j < 4; ++j)
            acc[i][j] = (K <= KC) ? part[i][j] : __fadd_rn(acc[i][j], part[i][j]);

    const int cb = n0 + 4*tx;
    #pragma unroll
    for (int i = 0; i < 8; ++i) {
        const int m = m0 + 8*ty + i;
        float* crow = C + (size_t)m * N + cb;
        if (cb + 3 < N) {
            *(float4*)crow = make_float4(acc[i][0], acc[i][1], acc[i][2], acc[i][3]);
        } else {
            #pragma unroll
            for (int j = 0; j < 4; ++j)
                if (cb + j < N) crow[j] = acc[i][j];
        }
    }
}

// ---------------------------------------------------------------------------
// 800x800 transpose: W2T[k][n] = W2[n][k]
// ---------------------------------------------------------------------------
__global__ __launch_bounds__(256)
void transpose800(const float* __restrict__ W2, float* __restrict__ W2T)
{
    __shared__ float t[32][33];
    const int tx  = threadIdx.x & 31;
    const int ty8 = threadIdx.x >> 5;
    const int bx = blockIdx.x * 32, by = blockIdx.y * 32;

    #pragma unroll
    for (int r = 0; r < 4; ++r) {
        int a = ty8 + r * 8;
        t[a][tx] = W2[(size_t)(by + a) * 800 + bx + tx];
    }
    __syncthreads();
    #pragma unroll
    for (int r = 0; r < 4; ++r) {
        int a = ty8 + r * 8;
        W2T[(size_t)(bx + a) * 800 + by + tx] = t[tx][a];
    }
}

// ---------------------------------------------------------------------------
// LIF scan for hidden layers (Nn=800), block per batch row, emits bitmask.
// ---------------------------------------------------------------------------
__global__ __launch_bounds__(256)
void lif_scan_hid(const float* __restrict__ Z,
                  const float* __restrict__ bias,
                  const float* __restrict__ budget,
                  float* __restrict__ mcarry,
                  float* __restrict__ Sout,
                  unsigned long long* __restrict__ bm,
                  int CT, int t0)
{
    const int b = blockIdx.x;
    const int tid = threadIdx.x;
    const int lane = tid & 63;
    const int wave = tid >> 6;

    float m[4], thr[4], bj[4];
    bool val[4];
    #pragma unroll
    for (int c = 0; c < 4; ++c) {
        const int j = c * 256 + tid;
        val[c] = (j < NHID);
        const int jj = val[c] ? j : 0;
        float bu = budget[jj];
        bu = fminf(fmaxf(bu, 0.01f), 1.0f);
        thr[c] = __fdiv_rn(1.0f, bu);
        bj[c]  = bias[jj];
        m[c]   = mcarry[b * NHID + jj];
    }

    for (int ct = 0; ct < CT; ++ct) {
        const size_t zbase = (size_t)ct * (BATCH * NHID) + (size_t)b * NHID;
        const size_t sbase = (size_t)(t0 + ct) * (BATCH * NHID) + (size_t)b * NHID;
        #pragma unroll
        for (int c = 0; c < 4; ++c) {
            const int j = c * 256 + tid;
            bool sp = false;
            if (val[c]) {
                float z = Z[zbase + j];
                float mm = __fadd_rn(__fadd_rn(__fmul_rn(0.95f, m[c]), z), bj[c]);
                sp = (mm > thr[c]);
                m[c] = sp ? 0.0f : mm;
                Sout[sbase + j] = sp ? 1.0f : 0.0f;
            }
            unsigned long long bits = __ballot(sp);
            if (bm && lane == 0) {
                const int W = c * 4 + wave;
                if (W < 13)
                    bm[((size_t)ct * BATCH + b) * 13 + W] = bits;
            }
        }
    }
    #pragma unroll
    for (int c = 0; c < 4; ++c)
        if (val[c]) mcarry[b * NHID + c * 256 + tid] = m[c];
}

// ---------------------------------------------------------------------------
// Sparse spike GEMM, 8 rows per block sharing W2T reads.
// Union bitmask walk (ascending k, wave-uniform); per-row uniform branches.
// Bit-exact: skipped k leaves chain unchanged; active k is fadd(part, w).
// ---------------------------------------------------------------------------
__global__ __launch_bounds__(256)
void spmm_spikes(const unsigned long long* __restrict__ bm, // [rows][13]
                 const float* __restrict__ W2T,             // [800][800]
                 float* __restrict__ Z,                     // [rows][800]
                 int rows)
{
    const int tid = threadIdx.x;
    const int row0 = blockIdx.x * GRP;
    const bool act = (tid < 200);
    const int n = 4 * (act ? tid : 0);

    float part[GRP][4], acc[GRP][4];
    #pragma unroll
    for (int r = 0; r < GRP; ++r)
        #pragma unroll
        for (int j = 0; j < 4; ++j) { part[r][j] = 0.0f; acc[r][j] = 0.0f; }

    int p = 0, nextb = KC;

    for (int w = 0; w < 13; ++w) {
        unsigned long long rm[GRP], u = 0ull;
        #pragma unroll
        for (int r = 0; r < GRP; ++r) {
            rm[r] = bm[(size_t)(row0 + r) * 13 + w];
            u |= rm[r];
        }
        while (u) {
            const int b = __ffsll((unsigned long long)u) - 1;
            u &= u - 1ull;
            const int k = w * 64 + b;
            while (k >= nextb) {          // close panel(s)
                #pragma unroll
                for (int r = 0; r < GRP; ++r)
                    #pragma unroll
                    for (int j = 0; j < 4; ++j) {
                        acc[r][j] = (p == 0) ? part[r][j]
                                             : __fadd_rn(acc[r][j], part[r][j]);
                        part[r][j] = 0.0f;
                    }
                ++p;
                nextb = (nextb == KC) ? 2 * KC : 0x7FFFFFFF;
            }
            const float4 wq = *(const float4*)(W2T + (size_t)k * NHID + n);
            #pragma unroll
            for (int r = 0; r < GRP; ++r) {
                if (__builtin_amdgcn_readfirstlane(
                        (unsigned)((rm[r] >> b) & 1ull))) {
                    part[r][0] = __fadd_rn(part[r][0], wq.x);
                    part[r][1] = __fadd_rn(part[r][1], wq.y);
                    part[r][2] = __fadd_rn(part[r][2], wq.z);
                    part[r][3] = __fadd_rn(part[r][3], wq.w);
                }
            }
        }
    }
    while (p < 3) {                       // close remaining panels (K=800 -> 3)
        #pragma unroll
        for (int r = 0; r < GRP; ++r)
            #pragma unroll
            for (int j = 0; j < 4; ++j) {
                acc[r][j] = (p == 0) ? part[r][j]
                                     : __fadd_rn(acc[r][j], part[r][j]);
                part[r][j] = 0.0f;
            }
        ++p;
    }
    if (act) {
        #pragma unroll
        for (int r = 0; r < GRP; ++r)
            *(float4*)(Z + (size_t)(row0 + r) * NHID + n) =
                make_float4(acc[r][0], acc[r][1], acc[r][2], acc[r][3]);
    }
}

// ---------------------------------------------------------------------------
__global__ __launch_bounds__(256)
void gemm3_f32(const float* __restrict__ S2, const float* __restrict__ W3,
               float* __restrict__ Z3, int rows)
{
    int gid = blockIdx.x * 256 + threadIdx.x;
    if (gid >= rows * NOUT) return;
    const int m = gid / NOUT;
    const int nn = gid % NOUT;
    const float* a = S2 + (size_t)m * NHID;
    const float* wr = W3 + (size_t)nn * NHID;

    float acc = 0.0f;
    for (int p0 = 0; p0 < NHID; p0 += KC) {
        const int pend = (p0 + KC < NHID) ? (p0 + KC) : NHID;
        float part = 0.0f;
        for (int k = p0; k < pend; ++k)
            part = __fmaf_rn(a[k], wr[k], part);
        acc = (p0 == 0) ? part : __fadd_rn(acc, part);
    }
    Z3[gid] = acc;
}

// ---------------------------------------------------------------------------
__global__ __launch_bounds__(256)
void lif_scan_small(const float* __restrict__ Z, const float* __restrict__ bias,
                    float* __restrict__ mcarry, float* __restrict__ Sout,
                    int CT, int t0)
{
    const int idx = blockIdx.x * blockDim.x + threadIdx.x;
    const int total = BATCH * NOUT;
    if (idx >= total) return;
    const int j = idx % NOUT;
    const float thr = 1.0f;
    const float bj = bias[j];

    float m = mcarry[idx];
    for (int ct = 0; ct < CT; ++ct) {
        float z = Z[(size_t)ct * total + idx];
        m = __fadd_rn(__fadd_rn(__fmul_rn(0.95f, m), z), bj);
        float s;
        if (m > thr) { s = 1.0f; m = 0.0f; }
        else         { s = 0.0f; }
        Sout[(size_t)(t0 + ct) * total + idx] = s;
    }
    mcarry[idx] = m;
}

// ---------------------------------------------------------------------------
__global__ __launch_bounds__(256)
void sum_t(const float* __restrict__ S3, float* __restrict__ out0)
{
    const int idx = blockIdx.x * blockDim.x + threadIdx.x;
    if (idx >= BATCH * NOUT) return;
    float s = 0.0f;
    for (int t = 0; t < TSTEPS; ++t)
        s += S3[(size_t)t * BATCH * NOUT + idx];
    out0[idx] = s;
}

// ---------------------------------------------------------------------------
extern "C" void kernel_launch(void* const* d_in, const int* in_sizes, int n_in,
                              void* d_out, int out_size, void* d_ws, size_t ws_size,
                              hipStream_t stream)
{
    const float* x       = (const float*)d_in[0];
    const float* W1      = (const float*)d_in[1];
    const float* b1      = (const float*)d_in[2];
    const float* W2      = (const float*)d_in[3];
    const float* b2      = (const float*)d_in[4];
    const float* W3      = (const float*)d_in[5];
    const float* b3      = (const float*)d_in[6];
    const float* budget1 = (const float*)d_in[7];
    const float* budget2 = (const float*)d_in[8];

    float* out  = (float*)d_out;
    float* out0 = out;
    float* out1 = out0 + BATCH * NOUT;
    float* out2 = out1 + (size_t)TSTEPS * BATCH * NHID;
    float* out3 = out2 + (size_t)TSTEPS * BATCH * NHID;

    const size_t nBH = (size_t)BATCH * NHID;
    const size_t nBO = (size_t)BATCH * NOUT;
    float* m1c = (float*)d_ws;
    float* m2c = m1c + nBH;
    float* m3c = m2c + nBH;
    float* w2t = m3c + nBO;
    unsigned long long* bmask = (unsigned long long*)(w2t + (size_t)NHID * NHID);
    float* Z = (float*)(bmask + (size_t)TSTEPS * BATCH * 13);

    const size_t fixedF = 2 * nBH + nBO + (size_t)NHID * NHID
                        + (size_t)TSTEPS * BATCH * 13 * 2;
    size_t availF = (ws_size / 4 > fixedF) ? (ws_size / 4 - fixedF) : 0;
    const size_t perT = (size_t)BATCH * (NHID + NOUT);
    int CT = (int)(availF / perT);
    if (CT > TSTEPS) CT = TSTEPS;
    if (CT < 1) CT = 1;

    hipMemsetAsync(d_ws, 0, (2 * nBH + nBO) * sizeof(float), stream);

    {
        dim3 tg(25, 25);
        transpose800<<<tg, 256, 0, stream>>>(W2, w2t);
    }

    for (int t0 = 0; t0 < TSTEPS; t0 += CT) {
        int ct = TSTEPS - t0 < CT ? TSTEPS - t0 : CT;
        int Mrows = ct * BATCH;
        float* Z3 = Z + (size_t)ct * BATCH * NHID;

        // layer 1: dense Z = x_chunk @ W1^T
        {
            dim3 grid(Mrows / 128, (NHID + 63) / 64);
            gemm_nt_f32<<<grid, 256, 0, stream>>>(
                x + (size_t)t0 * BATCH * NIN, W1, Z, Mrows, NHID, NIN);
        }
        lif_scan_hid<<<BATCH, 256, 0, stream>>>(
            Z, b1, budget1, m1c, out1, bmask, ct, t0);

        // layer 2: sparse Z = s1_chunk @ W2^T via bitmask (8 rows/block)
        spmm_spikes<<<Mrows / GRP, 256, 0, stream>>>(bmask, w2t, Z, Mrows);
        lif_scan_hid<<<BATCH, 256, 0, stream>>>(
            Z, b2, budget2, m2c, out2, nullptr, ct, t0);

        // layer 3
        gemm3_f32<<<(Mrows * NOUT + 255) / 256, 256, 0, stream>>>(
            out2 + (size_t)t0 * BATCH * NHID, W3, Z3, Mrows);
        lif_scan_small<<<(BATCH * NOUT + 255) / 256, 256, 0, stream>>>(
            Z3, b3, m3c, out3, ct, t0);
    }

    sum_t<<<(BATCH * NOUT + 255) / 256, 256, 0, stream>>>(out3, out0);
}

// Round 9
// 980.945 us; speedup vs baseline: 3.6696x; 1.5728x over previous
//
#include <hip/hip_runtime.h>

#define BATCH   512
#define TSTEPS  50
#define NIN     784
#define NHID    800
#define NOUT    10
#define KC      384   // OpenBLAS SGEMM_DEFAULT_Q — panel folds at k=384, 768
#define GRP     8     // rows per spmm block

// ---------------------------------------------------------------------------
// Dense f32 GEMM (NT), OpenBLAS-rounding-exact (layer 1).
// Round-5 structure (128x64 tile, 8x4 micro, BK=8, k-major LDS) + LDS
// double-buffer: one barrier per k-chunk instead of two.
// NOTE: no 2nd __launch_bounds__ arg — (256,4) caps VGPR at 64 and spills.
// Per element: ascending-k FMA chain per KC-panel; C = ((P1+P2)+P3).
// Requires M%128==0, K%8==0.
// ---------------------------------------------------------------------------
__global__ __launch_bounds__(256)
void gemm_nt_f32(const float* __restrict__ A, const float* __restrict__ B,
                 float* __restrict__ C, int M, int N, int K)
{
    __shared__ float As[2][8][132];   // [buf][k][m]
    __shared__ float Bs[2][8][68];    // [buf][k][n]

    const int tid = threadIdx.x;
    const int tx = tid & 15;        // n micro: cols 4*tx
    const int ty = tid >> 4;        // m micro: rows 8*ty
    const int m0 = blockIdx.x * 128;
    const int n0 = blockIdx.y * 64;

    const int arow = tid >> 1;          // 0..127
    const int akq  = (tid & 1) * 4;     // 0 or 4
    const int brow = tid >> 2;          // 0..63
    const int bkq  = (tid & 3) * 2;     // 0,2,4,6

    const float* Aptr = A + (size_t)(m0 + arow) * K + akq;
    const float* Bptr = B + (size_t)(n0 + brow) * K + bkq;
    const bool bval = (n0 + brow) < N;

    float part[8][4];   // current KC-panel chain
    float acc[8][4];    // folded closed panels
    #pragma unroll
    for (int i = 0; i < 8; ++i)
        #pragma unroll
        for (int j = 0; j < 4; ++j) part[i][j] = 0.0f;

    // chunk 0 -> buf 0
    {
        float4 av = *(const float4*)(Aptr);
        float2 bv = bval ? *(const float2*)(Bptr) : make_float2(0.f, 0.f);
        As[0][akq+0][arow] = av.x; As[0][akq+1][arow] = av.y;
        As[0][akq+2][arow] = av.z; As[0][akq+3][arow] = av.w;
        Bs[0][bkq+0][brow] = bv.x; Bs[0][bkq+1][brow] = bv.y;
    }
    __syncthreads();

    int cur = 0;
    for (int k0 = 0; k0 < K; k0 += 8) {
        const bool last = (k0 + 8 >= K);

        // prefetch next chunk into registers
        float4 av; float2 bv;
        if (!last) {
            av = *(const float4*)(Aptr + k0 + 8);
            bv = bval ? *(const float2*)(Bptr + k0 + 8) : make_float2(0.f, 0.f);
        }

        // KC-panel fold (uniform branch; k0 in {384, 768})
        if (k0 == 384 || k0 == 768) {
            #pragma unroll
            for (int i = 0; i < 8; ++i)
                #pragma unroll
                for (int j = 0; j < 4; ++j) {
                    acc[i][j] = (k0 == 384) ? part[i][j]
                                            : __fadd_rn(acc[i][j], part[i][j]);
                    part[i][j] = 0.0f;
                }
        }

        #pragma unroll
        for (int kk = 0; kk < 8; ++kk) {
            float a[8], b[4];
            *(float4*)&a[0] = *(const float4*)&As[cur][kk][8*ty];
            *(float4*)&a[4] = *(const float4*)&As[cur][kk][8*ty + 4];
            *(float4*)&b[0] = *(const float4*)&Bs[cur][kk][4*tx];
            #pragma unroll
            for (int i = 0; i < 8; ++i)
                #pragma unroll
                for (int j = 0; j < 4; ++j)
                    part[i][j] = __fmaf_rn(a[i], b[j], part[i][j]);
        }

        if (!last) {
            const int nx = cur ^ 1;
            As[nx][akq+0][arow] = av.x; As[nx][akq+1][arow] = av.y;
            As[nx][akq+2][arow] = av.z; As[nx][akq+3][arow] = av.w;
            Bs[nx][bkq+0][brow] = bv.x; Bs[nx][bkq+1][brow] = bv.y;
            __syncthreads();
        }
        cur ^= 1;
    }

    #pragma unroll
    for (int i = 0; i < 8; ++i)
        #pragma unroll
        for (int j = 0; j < 4; ++j)
            acc[i][j] = (K <= KC) ? part[i][j] : __fadd_rn(acc[i][j], part[i][j]);

    const int cb = n0 + 4*tx;
    #pragma unroll
    for (int i = 0; i < 8; ++i) {
        const int m = m0 + 8*ty + i;
        float* crow = C + (size_t)m * N + cb;
        if (cb + 3 < N) {
            *(float4*)crow = make_float4(acc[i][0], acc[i][1], acc[i][2], acc[i][3]);
        } else {
            #pragma unroll
            for (int j = 0; j < 4; ++j)
                if (cb + j < N) crow[j] = acc[i][j];
        }
    }
}

// ---------------------------------------------------------------------------
// 800x800 transpose: W2T[k][n] = W2[n][k]
// ---------------------------------------------------------------------------
__global__ __launch_bounds__(256)
void transpose800(const float* __restrict__ W2, float* __restrict__ W2T)
{
    __shared__ float t[32][33];
    const int tx  = threadIdx.x & 31;
    const int ty8 = threadIdx.x >> 5;
    const int bx = blockIdx.x * 32, by = blockIdx.y * 32;

    #pragma unroll
    for (int r = 0; r < 4; ++r) {
        int a = ty8 + r * 8;
        t[a][tx] = W2[(size_t)(by + a) * 800 + bx + tx];
    }
    __syncthreads();
    #pragma unroll
    for (int r = 0; r < 4; ++r) {
        int a = ty8 + r * 8;
        W2T[(size_t)(bx + a) * 800 + by + tx] = t[tx][a];
    }
}

// ---------------------------------------------------------------------------
// LIF scan for hidden layers (Nn=800), block per batch row, emits bitmask.
// ---------------------------------------------------------------------------
__global__ __launch_bounds__(256)
void lif_scan_hid(const float* __restrict__ Z,
                  const float* __restrict__ bias,
                  const float* __restrict__ budget,
                  float* __restrict__ mcarry,
                  float* __restrict__ Sout,
                  unsigned long long* __restrict__ bm,
                  int CT, int t0)
{
    const int b = blockIdx.x;
    const int tid = threadIdx.x;
    const int lane = tid & 63;
    const int wave = tid >> 6;

    float m[4], thr[4], bj[4];
    bool val[4];
    #pragma unroll
    for (int c = 0; c < 4; ++c) {
        const int j = c * 256 + tid;
        val[c] = (j < NHID);
        const int jj = val[c] ? j : 0;
        float bu = budget[jj];
        bu = fminf(fmaxf(bu, 0.01f), 1.0f);
        thr[c] = __fdiv_rn(1.0f, bu);
        bj[c]  = bias[jj];
        m[c]   = mcarry[b * NHID + jj];
    }

    for (int ct = 0; ct < CT; ++ct) {
        const size_t zbase = (size_t)ct * (BATCH * NHID) + (size_t)b * NHID;
        const size_t sbase = (size_t)(t0 + ct) * (BATCH * NHID) + (size_t)b * NHID;
        #pragma unroll
        for (int c = 0; c < 4; ++c) {
            const int j = c * 256 + tid;
            bool sp = false;
            if (val[c]) {
                float z = Z[zbase + j];
                float mm = __fadd_rn(__fadd_rn(__fmul_rn(0.95f, m[c]), z), bj[c]);
                sp = (mm > thr[c]);
                m[c] = sp ? 0.0f : mm;
                Sout[sbase + j] = sp ? 1.0f : 0.0f;
            }
            unsigned long long bits = __ballot(sp);
            if (bm && lane == 0) {
                const int W = c * 4 + wave;
                if (W < 13)
                    bm[((size_t)ct * BATCH + b) * 13 + W] = bits;
            }
        }
    }
    #pragma unroll
    for (int c = 0; c < 4; ++c)
        if (val[c]) mcarry[b * NHID + c * 256 + tid] = m[c];
}

// ---------------------------------------------------------------------------
// Sparse spike GEMM, 8 rows/block sharing W2T reads. Branch-free inner loop:
// masks m_r in {0.0f,1.0f} staged in LDS; part[r] = fma(m_r, w, part[r]).
// fma(0,w,p)=p and fma(1,w,p)=fadd(p,w) bit-exactly -> preserves the
// reference per-element ascending-k chain. Panel folds are window-aligned
// (384=6*64, 768=12*64) so they live in the w-loop, not per-k.
// ---------------------------------------------------------------------------
__global__ __launch_bounds__(256)
void spmm_spikes(const unsigned long long* __restrict__ bm, // [rows][13]
                 const float* __restrict__ W2T,             // [800][800]
                 float* __restrict__ Z,                     // [rows][800]
                 int rows)
{
    __shared__ float fm[13 * 64 * GRP];   // [w][b][r] mask floats (26 KB)

    const int tid = threadIdx.x;
    const int row0 = blockIdx.x * GRP;
    const bool act = (tid < 200);
    const int n = 4 * (act ? tid : 0);

    // pre-pass: expand bitmasks to float masks in LDS
    for (int q = tid; q < 13 * 64; q += 256) {
        const int w = q >> 6, b = q & 63;
        #pragma unroll
        for (int r = 0; r < GRP; ++r) {
            const unsigned long long mr = bm[(size_t)(row0 + r) * 13 + w];
            fm[q * GRP + r] = (float)((mr >> b) & 1ull);
        }
    }
    __syncthreads();

    float part[GRP][4], acc[GRP][4];
    #pragma unroll
    for (int r = 0; r < GRP; ++r)
        #pragma unroll
        for (int j = 0; j < 4; ++j) { part[r][j] = 0.0f; acc[r][j] = 0.0f; }

    int p = 0;
    for (int w = 0; w < 13; ++w) {
        if (w == 6 || w == 12) {          // close panel at k=384 / k=768
            #pragma unroll
            for (int r = 0; r < GRP; ++r)
                #pragma unroll
                for (int j = 0; j < 4; ++j) {
                    acc[r][j] = (p == 0) ? part[r][j]
                                         : __fadd_rn(acc[r][j], part[r][j]);
                    part[r][j] = 0.0f;
                }
            ++p;
        }
        unsigned long long u = 0ull;
        #pragma unroll
        for (int r = 0; r < GRP; ++r)
            u |= bm[(size_t)(row0 + r) * 13 + w];

        while (u) {
            const int b = __ffsll(u) - 1;
            u &= u - 1ull;
            const int k = (w << 6) + b;
            const float4 wq = *(const float4*)(W2T + (size_t)k * NHID + n);
            float marr[GRP];
            *(float4*)&marr[0] = *(const float4*)&fm[k * GRP];
            *(float4*)&marr[4] = *(const float4*)&fm[k * GRP + 4];
            #pragma unroll
            for (int r = 0; r < GRP; ++r) {
                part[r][0] = __fmaf_rn(marr[r], wq.x, part[r][0]);
                part[r][1] = __fmaf_rn(marr[r], wq.y, part[r][1]);
                part[r][2] = __fmaf_rn(marr[r], wq.z, part[r][2]);
                part[r][3] = __fmaf_rn(marr[r], wq.w, part[r][3]);
            }
        }
    }
    // close last panel (p==2 here for K=800)
    #pragma unroll
    for (int r = 0; r < GRP; ++r)
        #pragma unroll
        for (int j = 0; j < 4; ++j)
            acc[r][j] = (p == 0) ? part[r][j]
                                 : __fadd_rn(acc[r][j], part[r][j]);

    if (act) {
        #pragma unroll
        for (int r = 0; r < GRP; ++r)
            *(float4*)(Z + (size_t)(row0 + r) * NHID + n) =
                make_float4(acc[r][0], acc[r][1], acc[r][2], acc[r][3]);
    }
}

// ---------------------------------------------------------------------------
__global__ __launch_bounds__(256)
void gemm3_f32(const float* __restrict__ S2, const float* __restrict__ W3,
               float* __restrict__ Z3, int rows)
{
    int gid = blockIdx.x * 256 + threadIdx.x;
    if (gid >= rows * NOUT) return;
    const int m = gid / NOUT;
    const int nn = gid % NOUT;
    const float* a = S2 + (size_t)m * NHID;
    const float* wr = W3 + (size_t)nn * NHID;

    float acc = 0.0f;
    for (int p0 = 0; p0 < NHID; p0 += KC) {
        const int pend = (p0 + KC < NHID) ? (p0 + KC) : NHID;
        float part = 0.0f;
        for (int k = p0; k < pend; ++k)
            part = __fmaf_rn(a[k], wr[k], part);
        acc = (p0 == 0) ? part : __fadd_rn(acc, part);
    }
    Z3[gid] = acc;
}

// ---------------------------------------------------------------------------
__global__ __launch_bounds__(256)
void lif_scan_small(const float* __restrict__ Z, const float* __restrict__ bias,
                    float* __restrict__ mcarry, float* __restrict__ Sout,
                    int CT, int t0)
{
    const int idx = blockIdx.x * blockDim.x + threadIdx.x;
    const int total = BATCH * NOUT;
    if (idx >= total) return;
    const int j = idx % NOUT;
    const float thr = 1.0f;
    const float bj = bias[j];

    float m = mcarry[idx];
    for (int ct = 0; ct < CT; ++ct) {
        float z = Z[(size_t)ct * total + idx];
        m = __fadd_rn(__fadd_rn(__fmul_rn(0.95f, m), z), bj);
        float s;
        if (m > thr) { s = 1.0f; m = 0.0f; }
        else         { s = 0.0f; }
        Sout[(size_t)(t0 + ct) * total + idx] = s;
    }
    mcarry[idx] = m;
}

// ---------------------------------------------------------------------------
__global__ __launch_bounds__(256)
void sum_t(const float* __restrict__ S3, float* __restrict__ out0)
{
    const int idx = blockIdx.x * blockDim.x + threadIdx.x;
    if (idx >= BATCH * NOUT) return;
    float s = 0.0f;
    for (int t = 0; t < TSTEPS; ++t)
        s += S3[(size_t)t * BATCH * NOUT + idx];
    out0[idx] = s;
}

// ---------------------------------------------------------------------------
extern "C" void kernel_launch(void* const* d_in, const int* in_sizes, int n_in,
                              void* d_out, int out_size, void* d_ws, size_t ws_size,
                              hipStream_t stream)
{
    const float* x       = (const float*)d_in[0];
    const float* W1      = (const float*)d_in[1];
    const float* b1      = (const float*)d_in[2];
    const float* W2      = (const float*)d_in[3];
    const float* b2      = (const float*)d_in[4];
    const float* W3      = (const float*)d_in[5];
    const float* b3      = (const float*)d_in[6];
    const float* budget1 = (const float*)d_in[7];
    const float* budget2 = (const float*)d_in[8];

    float* out  = (float*)d_out;
    float* out0 = out;
    float* out1 = out0 + BATCH * NOUT;
    float* out2 = out1 + (size_t)TSTEPS * BATCH * NHID;
    float* out3 = out2 + (size_t)TSTEPS * BATCH * NHID;

    const size_t nBH = (size_t)BATCH * NHID;
    const size_t nBO = (size_t)BATCH * NOUT;
    float* m1c = (float*)d_ws;
    float* m2c = m1c + nBH;
    float* m3c = m2c + nBH;
    float* w2t = m3c + nBO;
    unsigned long long* bmask = (unsigned long long*)(w2t + (size_t)NHID * NHID);
    float* Z = (float*)(bmask + (size_t)TSTEPS * BATCH * 13);

    const size_t fixedF = 2 * nBH + nBO + (size_t)NHID * NHID
                        + (size_t)TSTEPS * BATCH * 13 * 2;
    size_t availF = (ws_size / 4 > fixedF) ? (ws_size / 4 - fixedF) : 0;
    const size_t perT = (size_t)BATCH * (NHID + NOUT);
    int CT = (int)(availF / perT);
    if (CT > TSTEPS) CT = TSTEPS;
    if (CT < 1) CT = 1;

    hipMemsetAsync(d_ws, 0, (2 * nBH + nBO) * sizeof(float), stream);

    {
        dim3 tg(25, 25);
        transpose800<<<tg, 256, 0, stream>>>(W2, w2t);
    }

    for (int t0 = 0; t0 < TSTEPS; t0 += CT) {
        int ct = TSTEPS - t0 < CT ? TSTEPS - t0 : CT;
        int Mrows = ct * BATCH;
        float* Z3 = Z + (size_t)ct * BATCH * NHID;

        // layer 1: dense Z = x_chunk @ W1^T
        {
            dim3 grid(Mrows / 128, (NHID + 63) / 64);
            gemm_nt_f32<<<grid, 256, 0, stream>>>(
                x + (size_t)t0 * BATCH * NIN, W1, Z, Mrows, NHID, NIN);
        }
        lif_scan_hid<<<BATCH, 256, 0, stream>>>(
            Z, b1, budget1, m1c, out1, bmask, ct, t0);

        // layer 2: sparse Z = s1_chunk @ W2^T via LDS float masks
        spmm_spikes<<<Mrows / GRP, 256, 0, stream>>>(bmask, w2t, Z, Mrows);
        lif_scan_hid<<<BATCH, 256, 0, stream>>>(
            Z, b2, budget2, m2c, out2, nullptr, ct, t0);

        // layer 3
        gemm3_f32<<<(Mrows * NOUT + 255) / 256, 256, 0, stream>>>(
            out2 + (size_t)t0 * BATCH * NHID, W3, Z3, Mrows);
        lif_scan_small<<<(BATCH * NOUT + 255) / 256, 256, 0, stream>>>(
            Z3, b3, m3c, out3, ct, t0);
    }

    sum_t<<<(BATCH * NOUT + 255) / 256, 256, 0, stream>>>(out3, out0);
}

// Round 10
// 937.194 us; speedup vs baseline: 3.8409x; 1.0467x over previous
//
#include <hip/hip_runtime.h>

#define BATCH   512
#define TSTEPS  50
#define NIN     784
#define NHID    800
#define NOUT    10
#define KC      384   // OpenBLAS SGEMM_DEFAULT_Q — panel folds at k=384, 768
#define GRP     8     // rows per spmm block

#define BM 128
#define BN 64
#define BK 8

// ---------------------------------------------------------------------------
// Dense f32 GEMM (NT), OpenBLAS-rounding-exact (layer 1).
// EXACT round-5 structure: 128x64 tile, 8x4 micro, BK=8, k-major LDS,
// register prefetch, (256,4). Proven: 489 us, VGPR=64 (fits the (256,4)
// 64-VGPR cap exactly), 0 bank conflicts. Do not touch.
// Per element: ascending-k FMA chain per KC-panel; C = ((P1+P2)+P3).
// ---------------------------------------------------------------------------
__global__ __launch_bounds__(256, 4)
void gemm_nt_f32(const float* __restrict__ A, const float* __restrict__ B,
                 float* __restrict__ C, int M, int N, int K)
{
    __shared__ float As[BK][BM + 4];   // [k][m], 8 x 132
    __shared__ float Bs[BK][BN + 4];   // [k][n], 8 x 68

    const int tid = threadIdx.x;
    const int tx = tid & 15;        // n micro: cols 4*tx .. 4*tx+3
    const int ty = tid >> 4;        // m micro: rows 8*ty .. 8*ty+7
    const int m0 = blockIdx.x * BM;
    const int n0 = blockIdx.y * BN;

    const int arow = tid >> 1;          // 0..127
    const int akq  = (tid & 1) * 4;     // 0 or 4
    const int brow = tid >> 2;          // 0..63
    const int bkq  = (tid & 3) * 2;     // 0,2,4,6

    const float* Aptr = A + (size_t)(m0 + arow) * K + akq;
    const float* Bptr = B + (size_t)(n0 + brow) * K + bkq;
    const bool bval = (n0 + brow) < N;

    float part[8][4];   // current KC-panel chain
    float acc[8][4];    // folded closed panels
    #pragma unroll
    for (int i = 0; i < 8; ++i)
        #pragma unroll
        for (int j = 0; j < 4; ++j) part[i][j] = 0.0f;

    float4 av = *(const float4*)(Aptr);
    float2 bv = bval ? *(const float2*)(Bptr) : make_float2(0.f, 0.f);

    for (int k0 = 0; k0 < K; k0 += BK) {
        __syncthreads();
        As[akq+0][arow] = av.x; As[akq+1][arow] = av.y;
        As[akq+2][arow] = av.z; As[akq+3][arow] = av.w;
        Bs[bkq+0][brow] = bv.x; Bs[bkq+1][brow] = bv.y;
        __syncthreads();

        // prefetch next chunk (hides under the 8x32 FMA block)
        if (k0 + BK < K) {
            av = *(const float4*)(Aptr + k0 + BK);
            bv = bval ? *(const float2*)(Bptr + k0 + BK) : make_float2(0.f, 0.f);
        }

        // KC-panel fold (uniform branch; k0 in {384, 768})
        if (k0 == 384 || k0 == 768) {
            #pragma unroll
            for (int i = 0; i < 8; ++i)
                #pragma unroll
                for (int j = 0; j < 4; ++j) {
                    acc[i][j] = (k0 == 384) ? part[i][j]
                                            : __fadd_rn(acc[i][j], part[i][j]);
                    part[i][j] = 0.0f;
                }
        }

        #pragma unroll
        for (int kk = 0; kk < BK; ++kk) {
            float a[8], b[4];
            *(float4*)&a[0] = *(const float4*)&As[kk][8*ty];
            *(float4*)&a[4] = *(const float4*)&As[kk][8*ty + 4];
            *(float4*)&b[0] = *(const float4*)&Bs[kk][4*tx];
            #pragma unroll
            for (int i = 0; i < 8; ++i)
                #pragma unroll
                for (int j = 0; j < 4; ++j)
                    part[i][j] = __fmaf_rn(a[i], b[j], part[i][j]);
        }
    }

    #pragma unroll
    for (int i = 0; i < 8; ++i)
        #pragma unroll
        for (int j = 0; j < 4; ++j)
            acc[i][j] = (K <= KC) ? part[i][j] : __fadd_rn(acc[i][j], part[i][j]);

    const int cb = n0 + 4*tx;
    #pragma unroll
    for (int i = 0; i < 8; ++i) {
        const int m = m0 + 8*ty + i;
        float* crow = C + (size_t)m * N + cb;
        if (cb + 3 < N) {
            *(float4*)crow = make_float4(acc[i][0], acc[i][1], acc[i][2], acc[i][3]);
        } else {
            #pragma unroll
            for (int j = 0; j < 4; ++j)
                if (cb + j < N) crow[j] = acc[i][j];
        }
    }
}

// ---------------------------------------------------------------------------
// 800x800 transpose: W2T[k][n] = W2[n][k]
// ---------------------------------------------------------------------------
__global__ __launch_bounds__(256)
void transpose800(const float* __restrict__ W2, float* __restrict__ W2T)
{
    __shared__ float t[32][33];
    const int tx  = threadIdx.x & 31;
    const int ty8 = threadIdx.x >> 5;
    const int bx = blockIdx.x * 32, by = blockIdx.y * 32;

    #pragma unroll
    for (int r = 0; r < 4; ++r) {
        int a = ty8 + r * 8;
        t[a][tx] = W2[(size_t)(by + a) * 800 + bx + tx];
    }
    __syncthreads();
    #pragma unroll
    for (int r = 0; r < 4; ++r) {
        int a = ty8 + r * 8;
        W2T[(size_t)(bx + a) * 800 + by + tx] = t[tx][a];
    }
}

// ---------------------------------------------------------------------------
// LIF scan for hidden layers (Nn=800), block per batch row, emits bitmask.
// ---------------------------------------------------------------------------
__global__ __launch_bounds__(256)
void lif_scan_hid(const float* __restrict__ Z,
                  const float* __restrict__ bias,
                  const float* __restrict__ budget,
                  float* __restrict__ mcarry,
                  float* __restrict__ Sout,
                  unsigned long long* __restrict__ bm,
                  int CT, int t0)
{
    const int b = blockIdx.x;
    const int tid = threadIdx.x;
    const int lane = tid & 63;
    const int wave = tid >> 6;

    float m[4], thr[4], bj[4];
    bool val[4];
    #pragma unroll
    for (int c = 0; c < 4; ++c) {
        const int j = c * 256 + tid;
        val[c] = (j < NHID);
        const int jj = val[c] ? j : 0;
        float bu = budget[jj];
        bu = fminf(fmaxf(bu, 0.01f), 1.0f);
        thr[c] = __fdiv_rn(1.0f, bu);
        bj[c]  = bias[jj];
        m[c]   = mcarry[b * NHID + jj];
    }

    for (int ct = 0; ct < CT; ++ct) {
        const size_t zbase = (size_t)ct * (BATCH * NHID) + (size_t)b * NHID;
        const size_t sbase = (size_t)(t0 + ct) * (BATCH * NHID) + (size_t)b * NHID;
        #pragma unroll
        for (int c = 0; c < 4; ++c) {
            const int j = c * 256 + tid;
            bool sp = false;
            if (val[c]) {
                float z = Z[zbase + j];
                float mm = __fadd_rn(__fadd_rn(__fmul_rn(0.95f, m[c]), z), bj[c]);
                sp = (mm > thr[c]);
                m[c] = sp ? 0.0f : mm;
                Sout[sbase + j] = sp ? 1.0f : 0.0f;
            }
            unsigned long long bits = __ballot(sp);
            if (bm && lane == 0) {
                const int W = c * 4 + wave;
                if (W < 13)
                    bm[((size_t)ct * BATCH + b) * 13 + W] = bits;
            }
        }
    }
    #pragma unroll
    for (int c = 0; c < 4; ++c)
        if (val[c]) mcarry[b * NHID + c * 256 + tid] = m[c];
}

// ---------------------------------------------------------------------------
// Sparse spike GEMM, 8 rows/block. Masks held in SGPRs (readfirstlane-forced
// uniform); union walk via scalar ffs; per-row 0/1 float from uniform bit
// feeds v_fmac — NO LDS traffic, SALU hides under the 32 FMAs.
// Bit-exact: fma(0,w,p)=p, fma(1,w,p)=fadd(p,w); p never -0 in these chains.
// Panel folds at window boundaries (384=6*64, 768=12*64).
// ---------------------------------------------------------------------------
__global__ __launch_bounds__(256)
void spmm_spikes(const unsigned long long* __restrict__ bm, // [rows][13]
                 const float* __restrict__ W2T,             // [800][800]
                 float* __restrict__ Z,                     // [rows][800]
                 int rows)
{
    const int tid = threadIdx.x;
    const int row0 = blockIdx.x * GRP;
    const bool act = (tid < 200);
    const int n = 4 * (act ? tid : 0);

    float part[GRP][4], acc[GRP][4];
    #pragma unroll
    for (int r = 0; r < GRP; ++r)
        #pragma unroll
        for (int j = 0; j < 4; ++j) { part[r][j] = 0.0f; acc[r][j] = 0.0f; }

    int p = 0;
    for (int w = 0; w < 13; ++w) {
        // close panel at k=384 / k=768 (window-aligned)
        if (w == 6 || w == 12) {
            #pragma unroll
            for (int r = 0; r < GRP; ++r)
                #pragma unroll
                for (int j = 0; j < 4; ++j) {
                    acc[r][j] = (p == 0) ? part[r][j]
                                         : __fadd_rn(acc[r][j], part[r][j]);
                    part[r][j] = 0.0f;
                }
            ++p;
        }

        // load the 8 row-masks for this window; force into SGPRs
        unsigned long long rm[GRP];
        unsigned long long u = 0ull;
        #pragma unroll
        for (int r = 0; r < GRP; ++r) {
            const unsigned long long v = bm[(size_t)(row0 + r) * 13 + w];
            const unsigned lo = __builtin_amdgcn_readfirstlane((unsigned)v);
            const unsigned hi = __builtin_amdgcn_readfirstlane((unsigned)(v >> 32));
            rm[r] = ((unsigned long long)hi << 32) | lo;
            u |= rm[r];
        }

        while (u) {
            const int b = __builtin_ctzll(u);
            u &= u - 1ull;
            const int k = (w << 6) + b;
            const float4 wq = *(const float4*)(W2T + (size_t)k * NHID + n);
            #pragma unroll
            for (int r = 0; r < GRP; ++r) {
                const float mf = ((rm[r] >> b) & 1ull) ? 1.0f : 0.0f;
                part[r][0] = __fmaf_rn(mf, wq.x, part[r][0]);
                part[r][1] = __fmaf_rn(mf, wq.y, part[r][1]);
                part[r][2] = __fmaf_rn(mf, wq.z, part[r][2]);
                part[r][3] = __fmaf_rn(mf, wq.w, part[r][3]);
            }
        }
    }
    // close last panel (p==2 here for K=800)
    #pragma unroll
    for (int r = 0; r < GRP; ++r)
        #pragma unroll
        for (int j = 0; j < 4; ++j)
            acc[r][j] = (p == 0) ? part[r][j]
                                 : __fadd_rn(acc[r][j], part[r][j]);

    if (act) {
        #pragma unroll
        for (int r = 0; r < GRP; ++r)
            *(float4*)(Z + (size_t)(row0 + r) * NHID + n) =
                make_float4(acc[r][0], acc[r][1], acc[r][2], acc[r][3]);
    }
}

// ---------------------------------------------------------------------------
__global__ __launch_bounds__(256)
void gemm3_f32(const float* __restrict__ S2, const float* __restrict__ W3,
               float* __restrict__ Z3, int rows)
{
    int gid = blockIdx.x * 256 + threadIdx.x;
    if (gid >= rows * NOUT) return;
    const int m = gid / NOUT;
    const int nn = gid % NOUT;
    const float* a = S2 + (size_t)m * NHID;
    const float* wr = W3 + (size_t)nn * NHID;

    float acc = 0.0f;
    for (int p0 = 0; p0 < NHID; p0 += KC) {
        const int pend = (p0 + KC < NHID) ? (p0 + KC) : NHID;
        float part = 0.0f;
        for (int k = p0; k < pend; ++k)
            part = __fmaf_rn(a[k], wr[k], part);
        acc = (p0 == 0) ? part : __fadd_rn(acc, part);
    }
    Z3[gid] = acc;
}

// ---------------------------------------------------------------------------
__global__ __launch_bounds__(256)
void lif_scan_small(const float* __restrict__ Z, const float* __restrict__ bias,
                    float* __restrict__ mcarry, float* __restrict__ Sout,
                    int CT, int t0)
{
    const int idx = blockIdx.x * blockDim.x + threadIdx.x;
    const int total = BATCH * NOUT;
    if (idx >= total) return;
    const int j = idx % NOUT;
    const float thr = 1.0f;
    const float bj = bias[j];

    float m = mcarry[idx];
    for (int ct = 0; ct < CT; ++ct) {
        float z = Z[(size_t)ct * total + idx];
        m = __fadd_rn(__fadd_rn(__fmul_rn(0.95f, m), z), bj);
        float s;
        if (m > thr) { s = 1.0f; m = 0.0f; }
        else         { s = 0.0f; }
        Sout[(size_t)(t0 + ct) * total + idx] = s;
    }
    mcarry[idx] = m;
}

// ---------------------------------------------------------------------------
__global__ __launch_bounds__(256)
void sum_t(const float* __restrict__ S3, float* __restrict__ out0)
{
    const int idx = blockIdx.x * blockDim.x + threadIdx.x;
    if (idx >= BATCH * NOUT) return;
    float s = 0.0f;
    for (int t = 0; t < TSTEPS; ++t)
        s += S3[(size_t)t * BATCH * NOUT + idx];
    out0[idx] = s;
}

// ---------------------------------------------------------------------------
extern "C" void kernel_launch(void* const* d_in, const int* in_sizes, int n_in,
                              void* d_out, int out_size, void* d_ws, size_t ws_size,
                              hipStream_t stream)
{
    const float* x       = (const float*)d_in[0];
    const float* W1      = (const float*)d_in[1];
    const float* b1      = (const float*)d_in[2];
    const float* W2      = (const float*)d_in[3];
    const float* b2      = (const float*)d_in[4];
    const float* W3      = (const float*)d_in[5];
    const float* b3      = (const float*)d_in[6];
    const float* budget1 = (const float*)d_in[7];
    const float* budget2 = (const float*)d_in[8];

    float* out  = (float*)d_out;
    float* out0 = out;
    float* out1 = out0 + BATCH * NOUT;
    float* out2 = out1 + (size_t)TSTEPS * BATCH * NHID;
    float* out3 = out2 + (size_t)TSTEPS * BATCH * NHID;

    const size_t nBH = (size_t)BATCH * NHID;
    const size_t nBO = (size_t)BATCH * NOUT;
    float* m1c = (float*)d_ws;
    float* m2c = m1c + nBH;
    float* m3c = m2c + nBH;
    float* w2t = m3c + nBO;
    unsigned long long* bmask = (unsigned long long*)(w2t + (size_t)NHID * NHID);
    float* Z = (float*)(bmask + (size_t)TSTEPS * BATCH * 13);

    const size_t fixedF = 2 * nBH + nBO + (size_t)NHID * NHID
                        + (size_t)TSTEPS * BATCH * 13 * 2;
    size_t availF = (ws_size / 4 > fixedF) ? (ws_size / 4 - fixedF) : 0;
    const size_t perT = (size_t)BATCH * (NHID + NOUT);
    int CT = (int)(availF / perT);
    if (CT > TSTEPS) CT = TSTEPS;
    if (CT < 1) CT = 1;

    hipMemsetAsync(d_ws, 0, (2 * nBH + nBO) * sizeof(float), stream);

    {
        dim3 tg(25, 25);
        transpose800<<<tg, 256, 0, stream>>>(W2, w2t);
    }

    for (int t0 = 0; t0 < TSTEPS; t0 += CT) {
        int ct = TSTEPS - t0 < CT ? TSTEPS - t0 : CT;
        int Mrows = ct * BATCH;
        float* Z3 = Z + (size_t)ct * BATCH * NHID;

        // layer 1: dense Z = x_chunk @ W1^T
        {
            dim3 grid(Mrows / BM, (NHID + BN - 1) / BN);
            gemm_nt_f32<<<grid, 256, 0, stream>>>(
                x + (size_t)t0 * BATCH * NIN, W1, Z, Mrows, NHID, NIN);
        }
        lif_scan_hid<<<BATCH, 256, 0, stream>>>(
            Z, b1, budget1, m1c, out1, bmask, ct, t0);

        // layer 2: sparse Z = s1_chunk @ W2^T via SGPR masks
        spmm_spikes<<<Mrows / GRP, 256, 0, stream>>>(bmask, w2t, Z, Mrows);
        lif_scan_hid<<<BATCH, 256, 0, stream>>>(
            Z, b2, budget2, m2c, out2, nullptr, ct, t0);

        // layer 3
        gemm3_f32<<<(Mrows * NOUT + 255) / 256, 256, 0, stream>>>(
            out2 + (size_t)t0 * BATCH * NHID, W3, Z3, Mrows);
        lif_scan_small<<<(BATCH * NOUT + 255) / 256, 256, 0, stream>>>(
            Z3, b3, m3c, out3, ct, t0);
    }

    sum_t<<<(BATCH * NOUT + 255) / 256, 256, 0, stream>>>(out3, out0);
}